// Round 4
// baseline (7081.788 us; speedup 1.0000x reference)
//
#include <hip/hip_runtime.h>
#include <stdint.h>

// ---------------------------------------------------------------------------
// MarketScoringUnit: LSTM(B=128,T=512,H=512) + attention + (mu, sigma) head.
// Round 4: lstm_rec sync split into cheap flag-spin (1 word/WG, s_sleep
// backoff) + ONE bulk tagged-data flight per step. Round-3's full-tile spin
// was saturating L3 (~37 TB/s of poll re-reads); this cuts poll BW ~10^4x.
// ---------------------------------------------------------------------------

using short8  = __attribute__((ext_vector_type(8))) short;   // 8 bf16 (4 VGPRs)
using short4v = __attribute__((ext_vector_type(4))) short;
using floatx4 = __attribute__((ext_vector_type(4))) float;

#define MFMA16(a, b, c) __builtin_amdgcn_mfma_f32_16x16x32_bf16((a), (b), (c), 0, 0, 0)

__device__ __forceinline__ unsigned short f2b(float f) {
    unsigned u = __float_as_uint(f);
    u += 0x7FFFu + ((u >> 16) & 1u);           // RNE
    return (unsigned short)(u >> 16);
}
__device__ __forceinline__ float b2f(unsigned short h) {
    return __uint_as_float(((unsigned)h) << 16);
}
__device__ __forceinline__ float sigm(float x) { return 1.0f / (1.0f + __expf(-x)); }
__device__ __forceinline__ float tanh_(float x) { return 1.0f - 2.0f / (__expf(2.0f * x) + 1.0f); }

// ---------------------------------------------------------------------------
// prep: fp32 -> bf16 conversions, U1 split into U1a/U1b, bias = b_ih + b_hh
// ---------------------------------------------------------------------------
__global__ __launch_bounds__(256) void prep(
    const float* __restrict__ x, const float* __restrict__ Wih, const float* __restrict__ Whh,
    const float* __restrict__ bih, const float* __restrict__ bhh,
    const float* __restrict__ U1, const float* __restrict__ U2,
    unsigned short* __restrict__ x_bf, unsigned short* __restrict__ Wih_bf,
    unsigned short* __restrict__ Whh_bf, unsigned short* __restrict__ U1a,
    unsigned short* __restrict__ U1b, unsigned short* __restrict__ U2b,
    float* __restrict__ bias)
{
    const long long NX4 = 33554432LL / 4;  // x as float4
    const long long NREST = 1048576LL + 1048576LL + 524288LL + 262144LL + 2048LL;
    const long long total = NX4 + NREST;
    for (long long u = (long long)blockIdx.x * 256 + threadIdx.x; u < total;
         u += (long long)gridDim.x * 256) {
        if (u < NX4) {
            float4 v = ((const float4*)x)[u];
            short4v o;
            o[0] = (short)f2b(v.x); o[1] = (short)f2b(v.y);
            o[2] = (short)f2b(v.z); o[3] = (short)f2b(v.w);
            *(short4v*)&x_bf[u * 4] = o;
        } else {
            long long i = u - NX4;
            if (i < 1048576) { Wih_bf[i] = f2b(Wih[i]); continue; }
            i -= 1048576;
            if (i < 1048576) { Whh_bf[i] = f2b(Whh[i]); continue; }
            i -= 1048576;
            if (i < 524288) {
                int row = (int)(i >> 10), col = (int)(i & 1023);
                if (col < 512) U1a[row * 512 + col] = f2b(U1[i]);
                else           U1b[row * 512 + (col - 512)] = f2b(U1[i]);
                continue;
            }
            i -= 524288;
            if (i < 262144) { U2b[i] = f2b(U2[i]); continue; }
            i -= 262144;
            bias[i] = bih[i] + bhh[i];
        }
    }
}

// ---------------------------------------------------------------------------
// gemm_bt: C[m][n] = sum_k A[m][k]*B[n][k] (+bias[n]); bf16 in/out, fp32 acc.
// 128x128 block tile, BK=64, 4 waves of 64x64.
// mode==1: scatter-store into xg layout [t][jg][b][c], c = gate*16 + (n&15),
//          jg = (n>>4)&31, gate = n>>9  (tile rows = 128 consecutive t, one b)
// ---------------------------------------------------------------------------
__global__ __launch_bounds__(256) void gemm_bt(
    const unsigned short* __restrict__ A, long long lda,
    const unsigned short* __restrict__ Bm, long long ldb,
    unsigned short* __restrict__ C, long long ldc,
    const float* __restrict__ bias, int mode)
{
    __shared__ __align__(16) unsigned short sbuf[2 * 128 * 72];
    unsigned short* At = sbuf;
    unsigned short* Bt = sbuf + 128 * 72;
    unsigned short* Ct = sbuf;  // alias, used after final sync

    const int m0 = blockIdx.x * 128, n0 = blockIdx.y * 128;
    const int tid = threadIdx.x;
    const int wv = tid >> 6, lane = tid & 63, l15 = lane & 15, q = lane >> 4;
    const int wm = wv & 1, wn = wv >> 1;

    floatx4 acc[4][4];
    for (int i = 0; i < 4; i++)
        for (int j = 0; j < 4; j++) acc[i][j] = (floatx4){0.f, 0.f, 0.f, 0.f};

    for (int k0 = 0; k0 < 512; k0 += 64) {
        for (int p = 0; p < 4; p++) {
            int idx = tid + p * 256;
            int row = idx >> 3, ch = idx & 7;
            *(short8*)&At[row * 72 + ch * 8] =
                *(const short8*)&A[(long long)(m0 + row) * lda + k0 + ch * 8];
            *(short8*)&Bt[row * 72 + ch * 8] =
                *(const short8*)&Bm[(long long)(n0 + row) * ldb + k0 + ch * 8];
        }
        __syncthreads();
        for (int ks = 0; ks < 64; ks += 32) {
            short8 af[4], bfv[4];
            for (int mi = 0; mi < 4; mi++)
                af[mi] = *(const short8*)&At[(wm * 64 + mi * 16 + l15) * 72 + ks + q * 8];
            for (int ni = 0; ni < 4; ni++)
                bfv[ni] = *(const short8*)&Bt[(wn * 64 + ni * 16 + l15) * 72 + ks + q * 8];
            for (int mi = 0; mi < 4; mi++)
                for (int ni = 0; ni < 4; ni++)
                    acc[mi][ni] = MFMA16(af[mi], bfv[ni], acc[mi][ni]);
        }
        __syncthreads();
    }

    float bv[4];
    for (int ni = 0; ni < 4; ni++)
        bv[ni] = bias ? bias[n0 + wn * 64 + ni * 16 + l15] : 0.0f;

    for (int mi = 0; mi < 4; mi++)
        for (int ni = 0; ni < 4; ni++)
            for (int r = 0; r < 4; r++)
                Ct[(wm * 64 + mi * 16 + q * 4 + r) * 128 + wn * 64 + ni * 16 + l15] =
                    f2b(acc[mi][ni][r] + bv[ni]);
    __syncthreads();

    const int tt0 = m0 & 511, bglob = m0 >> 9;
    for (int p = 0; p < 8; p++) {
        int idx = tid + p * 256;
        int row = idx >> 4, ch = idx & 15;
        if (mode) {
            int n = n0 + ch * 8;
            int gate = n >> 9, jg = (n >> 4) & 31, c0 = gate * 16 + (n & 15);
            long long dst = (((long long)(tt0 + row) * 32 + jg) * 128 + bglob) * 64 + c0;
            *(short8*)&C[dst] = *(const short8*)&Ct[row * 128 + ch * 8];
        } else {
            *(short8*)&C[(long long)(m0 + row) * ldc + n0 + ch * 8] =
                *(const short8*)&Ct[row * 128 + ch * 8];
        }
    }
}

// ---------------------------------------------------------------------------
// lstm_rec: persistent recurrence. 256 WGs = 8 batch-groups x 32 hid-groups.
// Each WG: 16 batches x 16 hidden, all 4 gates (N=64 cols). W_hh slice in
// VGPRs; c state in registers.
// Cross-WG handoff per step:
//   producer: tagged ring stores (relaxed agent) -> s_waitcnt vmcnt(0) ->
//             barrier -> ONE flags[t][bg] atomic_add (fire-and-forget)
//   consumer: tid0 spins on the single flag word (s_sleep backoff) ->
//             barrier -> ONE bulk flight of 16x8B tagged words (tags are a
//             safety net only; flag==32 implies data is at coherence point)
// ---------------------------------------------------------------------------
#define NBG 8
#define NJG 32
__global__ __launch_bounds__(256) void lstm_rec(
    const unsigned short* __restrict__ xg,   // [t][jg][b][c]  c = gate*16+hl
    const unsigned short* __restrict__ Whh,  // (2048, 512) bf16
    unsigned short* __restrict__ h_all,      // [b][t][h]  (128, 512, 512)
    unsigned long long* __restrict__ ring,   // [2][128][256] tagged pairs
    int* __restrict__ flags)                 // [512][NBG]
{
    __shared__ unsigned int At[2][16 * 264];  // packed bf16 pairs, stride 264

    const int tid = threadIdx.x;
    const int wv = tid >> 6, lane = tid & 63, l15 = lane & 15, q = lane >> 4;
    const int bg = blockIdx.x >> 5, jg = blockIdx.x & 31;
    const int b0 = bg * 16, hid0 = jg * 16;
    const int gate = l15 >> 2;                 // 0=i 1=f 2=g 3=o
    const int hl = wv * 4 + (l15 & 3);         // 0..15 within this jg
    const int hid = hid0 + hl;
    const long long jrow = (long long)gate * 512 + hid;

    short8 Wreg[16];
    for (int kk = 0; kk < 16; kk++)
        Wreg[kk] = *(const short8*)&Whh[jrow * 512 + kk * 32 + q * 8];

    unsigned long long* const rb0 = ring + (long long)b0 * 256;
    unsigned long long* const rb1 = ring + 32768 + (long long)b0 * 256;
    unsigned int* const ring32 = (unsigned int*)ring;

    float cst[4] = {0.f, 0.f, 0.f, 0.f};

    for (int t = 0; t < 512; t++) {
        // ---- prefetch xg (contiguous 2KB block per WG per step) ----
        const long long xbase =
            (((long long)t * 32 + jg) * 128 + b0) * 64 + gate * 16 + hl;
        float xv[4];
        #pragma unroll
        for (int r = 0; r < 4; r++)
            xv[r] = b2f(xg[xbase + (long long)(q * 4 + r) * 64]);

        floatx4 acc = (floatx4){0.f, 0.f, 0.f, 0.f};
        if (t > 0) {
            const unsigned want = (unsigned)(t - 1);
            // 1) cheap wait: one lane spins on one 4-byte flag word
            if (tid == 0) {
                while (__hip_atomic_load(&flags[(t - 1) * NBG + bg], __ATOMIC_RELAXED,
                                         __HIP_MEMORY_SCOPE_AGENT) < NJG)
                    __builtin_amdgcn_s_sleep(1);
            }
            __syncthreads();
            // 2) single bulk data flight (fresh by construction; tags = safety)
            unsigned long long* rb = ((t - 1) & 1) ? rb1 : rb0;
            unsigned long long w[16];
            #pragma unroll
            for (int i = 0; i < 16; i++)
                w[i] = __hip_atomic_load(&rb[tid + i * 256], __ATOMIC_RELAXED,
                                         __HIP_MEMORY_SCOPE_AGENT);
            while (true) {
                unsigned bad = 0;
                #pragma unroll
                for (int i = 0; i < 16; i++) {
                    unsigned lo = (unsigned)(w[i] >> 16) & 0xFFFFu;
                    unsigned hi = (unsigned)(w[i] >> 48);
                    bad |= (lo ^ want) | (hi ^ want);
                }
                if (!bad) break;
                __builtin_amdgcn_s_sleep(1);   // should essentially never loop
                #pragma unroll
                for (int i = 0; i < 16; i++) {
                    unsigned lo = (unsigned)(w[i] >> 16) & 0xFFFFu;
                    unsigned hi = (unsigned)(w[i] >> 48);
                    if ((lo ^ want) | (hi ^ want))
                        w[i] = __hip_atomic_load(&rb[tid + i * 256], __ATOMIC_RELAXED,
                                                 __HIP_MEMORY_SCOPE_AGENT);
                }
            }
            // pack two bf16 into one LDS word (strip tags)
            unsigned int* dst = &At[(t - 1) & 1][0];
            #pragma unroll
            for (int i = 0; i < 16; i++) {
                int idx = tid + i * 256;
                int row = idx >> 8, k = idx & 255;
                dst[row * 264 + k] =
                    (unsigned)(w[i] & 0xFFFFu) | ((unsigned)(w[i] >> 32) << 16);
            }
            __syncthreads();
            const unsigned int* ap = &At[(t - 1) & 1][l15 * 264 + q * 4];
            floatx4 a0 = (floatx4){0.f, 0.f, 0.f, 0.f};
            floatx4 a1 = (floatx4){0.f, 0.f, 0.f, 0.f};
            floatx4 a2 = (floatx4){0.f, 0.f, 0.f, 0.f};
            floatx4 a3 = (floatx4){0.f, 0.f, 0.f, 0.f};
            #pragma unroll
            for (int kk = 0; kk < 16; kk += 4) {
                a0 = MFMA16(*(const short8*)(ap + (kk + 0) * 16), Wreg[kk + 0], a0);
                a1 = MFMA16(*(const short8*)(ap + (kk + 1) * 16), Wreg[kk + 1], a1);
                a2 = MFMA16(*(const short8*)(ap + (kk + 2) * 16), Wreg[kk + 2], a2);
                a3 = MFMA16(*(const short8*)(ap + (kk + 3) * 16), Wreg[kk + 3], a3);
            }
            for (int r = 0; r < 4; r++) acc[r] = (a0[r] + a1[r]) + (a2[r] + a3[r]);
        }
        // pre-activations
        float p[4];
        #pragma unroll
        for (int r = 0; r < 4; r++) p[r] = acc[r] + xv[r];
        // gather the other gates via lane shuffles (i,f,g,o at n, n^4, n^8, n^12)
        float vf[4], vg[4], vo[4];
        #pragma unroll
        for (int r = 0; r < 4; r++) vf[r] = __shfl_xor(p[r], 4);
        #pragma unroll
        for (int r = 0; r < 4; r++) vg[r] = __shfl_xor(p[r], 8);
        #pragma unroll
        for (int r = 0; r < 4; r++) vo[r] = __shfl_xor(p[r], 12);
        if (gate == 0) {
            #pragma unroll
            for (int r = 0; r < 4; r++) {
                float ig = sigm(p[r]);
                float fg = sigm(vf[r]);
                float gv = tanh_(vg[r]);
                float og = sigm(vo[r]);
                cst[r] = fg * cst[r] + ig * gv;
                float hv = og * tanh_(cst[r]);
                unsigned short hb = f2b(hv);
                const int b = b0 + q * 4 + r;
                __hip_atomic_store(&ring32[(t & 1) * 65536 + b * 512 + hid],
                                   ((unsigned)t << 16) | hb, __ATOMIC_RELAXED,
                                   __HIP_MEMORY_SCOPE_AGENT);
                h_all[(long long)b * 262144 + (long long)t * 512 + hid] = hb;
            }
        }
        // publish: drain stores (per wave), all-wave barrier, one flag add
        asm volatile("s_waitcnt vmcnt(0)" ::: "memory");
        __syncthreads();
        if (tid == 0)
            __hip_atomic_fetch_add(&flags[t * NBG + bg], 1, __ATOMIC_RELAXED,
                                   __HIP_MEMORY_SCOPE_AGENT);
    }
}

// ---------------------------------------------------------------------------
// attn_e: e[b,t] = Ve . tanh(h@U1a^T + u1b[b] + x@U2^T), fused, 32 t per WG.
// ---------------------------------------------------------------------------
__global__ __launch_bounds__(256) void attn_e(
    const unsigned short* __restrict__ h_all,
    const unsigned short* __restrict__ x_bf,
    const unsigned short* __restrict__ U1a, const unsigned short* __restrict__ U2b,
    const unsigned short* __restrict__ u1b,  // bf16 (128,512)
    const float* __restrict__ Ve,
    float* __restrict__ e)
{
    __shared__ __align__(16) unsigned short Bt[512 * 40];
    __shared__ __align__(16) unsigned short At[32 * 40];
    __shared__ float ered[4][32];

    const int tid = threadIdx.x;
    const int wv = tid >> 6, lane = tid & 63, l15 = lane & 15, q = lane >> 4;
    const int b = blockIdx.x >> 4, t0 = (blockIdx.x & 15) * 32;

    floatx4 acc[2][8];
    for (int mi = 0; mi < 2; mi++)
        for (int ni = 0; ni < 8; ni++) acc[mi][ni] = (floatx4){0.f, 0.f, 0.f, 0.f};

    for (int it = 0; it < 32; it++) {
        const int phase = it >> 4, kk = (it & 15) * 32;
        const unsigned short* Asrc = phase ? x_bf : h_all;
        const unsigned short* Bsrc = phase ? U2b : U1a;
        __syncthreads();
        for (int idx = tid; idx < 2048; idx += 256) {
            int row = idx >> 2, ch = idx & 3;
            *(short8*)&Bt[row * 40 + ch * 8] =
                *(const short8*)&Bsrc[(long long)row * 512 + kk + ch * 8];
        }
        if (tid < 128) {
            int row = tid >> 2, ch = tid & 3;
            *(short8*)&At[row * 40 + ch * 8] =
                *(const short8*)&Asrc[(long long)(b * 512 + t0 + row) * 512 + kk + ch * 8];
        }
        __syncthreads();
        short8 af[2];
        for (int mi = 0; mi < 2; mi++)
            af[mi] = *(const short8*)&At[(mi * 16 + l15) * 40 + q * 8];
        for (int ni = 0; ni < 8; ni++) {
            short8 bfv = *(const short8*)&Bt[(wv * 128 + ni * 16 + l15) * 40 + q * 8];
            acc[0][ni] = MFMA16(af[0], bfv, acc[0][ni]);
            acc[1][ni] = MFMA16(af[1], bfv, acc[1][ni]);
        }
    }

    float s[2][4] = {{0.f, 0.f, 0.f, 0.f}, {0.f, 0.f, 0.f, 0.f}};
    for (int ni = 0; ni < 8; ni++) {
        int n = wv * 128 + ni * 16 + l15;
        float ub = b2f(u1b[b * 512 + n]);
        float vev = Ve[n];
        for (int mi = 0; mi < 2; mi++)
            for (int r = 0; r < 4; r++)
                s[mi][r] += vev * tanh_(acc[mi][ni][r] + ub);
    }
    for (int off = 1; off <= 8; off <<= 1)
        for (int mi = 0; mi < 2; mi++)
            for (int r = 0; r < 4; r++) s[mi][r] += __shfl_xor(s[mi][r], off);
    if (l15 == 0)
        for (int mi = 0; mi < 2; mi++)
            for (int r = 0; r < 4; r++) ered[wv][mi * 16 + q * 4 + r] = s[mi][r];
    __syncthreads();
    if (tid < 32)
        e[(long long)b * 512 + t0 + tid] =
            ered[0][tid] + ered[1][tid] + ered[2][tid] + ered[3][tid];
}

// ---------------------------------------------------------------------------
// attn_out: softmax over T, context = alpha.h, head -> mu, sigma. 1 WG per b.
// ---------------------------------------------------------------------------
__global__ __launch_bounds__(256) void attn_out(
    const float* __restrict__ e, const unsigned short* __restrict__ h_all,
    const float* __restrict__ Wout, const float* __restrict__ bout,
    float* __restrict__ outp)
{
    __shared__ float sm[512];
    __shared__ float red[8];
    const int b = blockIdx.x, tid = threadIdx.x;
    const int wv = tid >> 6, lane = tid & 63;

    float e0 = e[b * 512 + tid], e1 = e[b * 512 + 256 + tid];
    float mx = fmaxf(e0, e1);
    for (int off = 32; off; off >>= 1) mx = fmaxf(mx, __shfl_xor(mx, off));
    if (lane == 0) red[wv] = mx;
    __syncthreads();
    mx = fmaxf(fmaxf(red[0], red[1]), fmaxf(red[2], red[3]));

    float s0 = __expf(e0 - mx), s1 = __expf(e1 - mx);
    sm[tid] = s0; sm[256 + tid] = s1;
    float ss = s0 + s1;
    for (int off = 32; off; off >>= 1) ss += __shfl_xor(ss, off);
    if (lane == 0) red[4 + wv] = ss;
    __syncthreads();
    float inv = 1.0f / (red[4] + red[5] + red[6] + red[7]);

    const long long base = (long long)b * 262144;
    float a0 = 0.f, a1 = 0.f;
    for (int t = 0; t < 512; t++) {
        float al = sm[t];
        a0 += al * b2f(h_all[base + t * 512 + tid]);
        a1 += al * b2f(h_all[base + t * 512 + 256 + tid]);
    }
    a0 *= inv; a1 *= inv;

    float q0 = a0 * Wout[tid] + a1 * Wout[256 + tid];
    float q1 = a0 * Wout[512 + tid] + a1 * Wout[768 + tid];
    for (int off = 32; off; off >>= 1) { q0 += __shfl_xor(q0, off); q1 += __shfl_xor(q1, off); }
    __syncthreads();  // red reuse
    if (lane == 0) { red[wv] = q0; red[4 + wv] = q1; }
    __syncthreads();
    if (tid == 0) {
        float P0 = red[0] + red[1] + red[2] + red[3] + bout[0];
        float P1 = red[4] + red[5] + red[6] + red[7] + bout[1];
        outp[b] = P0;
        float sp = (P1 > 15.0f) ? P1 : log1pf(__expf(P1));
        outp[128 + b] = sp + 1e-5f;
    }
}

// ---------------------------------------------------------------------------
extern "C" void kernel_launch(void* const* d_in, const int* in_sizes, int n_in,
                              void* d_out, int out_size, void* d_ws, size_t ws_size,
                              hipStream_t stream)
{
    const float* x    = (const float*)d_in[0];
    const float* Wih  = (const float*)d_in[1];
    const float* Whh  = (const float*)d_in[2];
    const float* bih  = (const float*)d_in[3];
    const float* bhh  = (const float*)d_in[4];
    const float* Ve   = (const float*)d_in[5];
    const float* U1   = (const float*)d_in[6];
    const float* U2   = (const float*)d_in[7];
    const float* Wout = (const float*)d_in[8];
    const float* bout = (const float*)d_in[9];
    float* out = (float*)d_out;

    char* ws = (char*)d_ws;
    size_t off = 0;
    auto alloc = [&](size_t bytes) -> void* {
        void* p = ws + off;
        off += (bytes + 255) & ~(size_t)255;
        return p;
    };
    unsigned short* x_bf   = (unsigned short*)alloc(33554432ull * 2);
    unsigned short* Wih_bf = (unsigned short*)alloc(1048576ull * 2);
    unsigned short* Whh_bf = (unsigned short*)alloc(1048576ull * 2);
    unsigned short* U1a    = (unsigned short*)alloc(262144ull * 2);
    unsigned short* U1b    = (unsigned short*)alloc(262144ull * 2);
    unsigned short* U2b    = (unsigned short*)alloc(262144ull * 2);
    float*          bias   = (float*)alloc(2048ull * 4);
    unsigned short* xg     = (unsigned short*)alloc(134217728ull * 2);
    unsigned short* h_all  = (unsigned short*)alloc(33554432ull * 2);
    unsigned short* u1bv   = (unsigned short*)alloc(65536ull * 2);
    float*          e      = (float*)alloc(65536ull * 4);
    unsigned long long* ring = (unsigned long long*)alloc(65536ull * 8);  // 2x128x256 pairs
    int*            flags  = (int*)alloc(4096ull * 4);                    // [512][8]
    if (off > ws_size) return;  // workspace too small: fail safe (no corruption)

    hipMemsetAsync(flags, 0, 4096 * 4, stream);
    prep<<<4096, 256, 0, stream>>>(x, Wih, Whh, bih, bhh, U1, U2,
                                   x_bf, Wih_bf, Whh_bf, U1a, U1b, U2b, bias);
    // xg = x @ W_ih^T + b, scattered into [t][jg][b][c]
    gemm_bt<<<dim3(512, 16), 256, 0, stream>>>(x_bf, 512, Wih_bf, 512,
                                               xg, 2048, bias, 1);
    lstm_rec<<<256, 256, 0, stream>>>(xg, Whh_bf, h_all, ring, flags);
    // u1b = h_last @ U1b^T
    gemm_bt<<<dim3(1, 4), 256, 0, stream>>>(h_all + 511 * 512, 262144, U1b, 512,
                                            u1bv, 512, nullptr, 0);
    attn_e<<<2048, 256, 0, stream>>>(h_all, x_bf, U1a, U2b, u1bv, Ve, e);
    attn_out<<<128, 256, 0, stream>>>(e, h_all, Wout, bout, out);
}

// Round 5
// 3796.041 us; speedup vs baseline: 1.8656x; 1.8656x over previous
//
#include <hip/hip_runtime.h>
#include <stdint.h>

// ---------------------------------------------------------------------------
// MarketScoringUnit: LSTM(B=128,T=512,H=512) + attention + (mu, sigma) head.
// Round 5 lstm_rec: eager per-WAVE sentinel sync. Producer wave drains its
// raw (untagged) ring stores with vmcnt(0), then stores one sentinel word;
// consumer waves poll 128 sentinels each round (8B/lane, no sleep, no
// barrier, no RMW) and bulk-load the raw tile once. Fixes R3's 38 TB/s
// poll congestion AND avoids R4's flag+sleep+barrier serialization.
// ---------------------------------------------------------------------------

using short8  = __attribute__((ext_vector_type(8))) short;   // 8 bf16 (4 VGPRs)
using short4v = __attribute__((ext_vector_type(4))) short;
using floatx4 = __attribute__((ext_vector_type(4))) float;

#define MFMA16(a, b, c) __builtin_amdgcn_mfma_f32_16x16x32_bf16((a), (b), (c), 0, 0, 0)

__device__ __forceinline__ unsigned short f2b(float f) {
    unsigned u = __float_as_uint(f);
    u += 0x7FFFu + ((u >> 16) & 1u);           // RNE
    return (unsigned short)(u >> 16);
}
__device__ __forceinline__ float b2f(unsigned short h) {
    return __uint_as_float(((unsigned)h) << 16);
}
__device__ __forceinline__ float sigm(float x) { return 1.0f / (1.0f + __expf(-x)); }
__device__ __forceinline__ float tanh_(float x) { return 1.0f - 2.0f / (__expf(2.0f * x) + 1.0f); }

// ---------------------------------------------------------------------------
// prep: fp32 -> bf16 conversions, U1 split into U1a/U1b, bias = b_ih + b_hh
// ---------------------------------------------------------------------------
__global__ __launch_bounds__(256) void prep(
    const float* __restrict__ x, const float* __restrict__ Wih, const float* __restrict__ Whh,
    const float* __restrict__ bih, const float* __restrict__ bhh,
    const float* __restrict__ U1, const float* __restrict__ U2,
    unsigned short* __restrict__ x_bf, unsigned short* __restrict__ Wih_bf,
    unsigned short* __restrict__ Whh_bf, unsigned short* __restrict__ U1a,
    unsigned short* __restrict__ U1b, unsigned short* __restrict__ U2b,
    float* __restrict__ bias)
{
    const long long NX4 = 33554432LL / 4;  // x as float4
    const long long NREST = 1048576LL + 1048576LL + 524288LL + 262144LL + 2048LL;
    const long long total = NX4 + NREST;
    for (long long u = (long long)blockIdx.x * 256 + threadIdx.x; u < total;
         u += (long long)gridDim.x * 256) {
        if (u < NX4) {
            float4 v = ((const float4*)x)[u];
            short4v o;
            o[0] = (short)f2b(v.x); o[1] = (short)f2b(v.y);
            o[2] = (short)f2b(v.z); o[3] = (short)f2b(v.w);
            *(short4v*)&x_bf[u * 4] = o;
        } else {
            long long i = u - NX4;
            if (i < 1048576) { Wih_bf[i] = f2b(Wih[i]); continue; }
            i -= 1048576;
            if (i < 1048576) { Whh_bf[i] = f2b(Whh[i]); continue; }
            i -= 1048576;
            if (i < 524288) {
                int row = (int)(i >> 10), col = (int)(i & 1023);
                if (col < 512) U1a[row * 512 + col] = f2b(U1[i]);
                else           U1b[row * 512 + (col - 512)] = f2b(U1[i]);
                continue;
            }
            i -= 524288;
            if (i < 262144) { U2b[i] = f2b(U2[i]); continue; }
            i -= 262144;
            bias[i] = bih[i] + bhh[i];
        }
    }
}

// ---------------------------------------------------------------------------
// gemm_bt: C[m][n] = sum_k A[m][k]*B[n][k] (+bias[n]); bf16 in/out, fp32 acc.
// 128x128 block tile, BK=64, 4 waves of 64x64.
// mode==1: scatter-store into xg layout [t][jg][b][c], c = gate*16 + (n&15),
//          jg = (n>>4)&31, gate = n>>9  (tile rows = 128 consecutive t, one b)
// ---------------------------------------------------------------------------
__global__ __launch_bounds__(256) void gemm_bt(
    const unsigned short* __restrict__ A, long long lda,
    const unsigned short* __restrict__ Bm, long long ldb,
    unsigned short* __restrict__ C, long long ldc,
    const float* __restrict__ bias, int mode)
{
    __shared__ __align__(16) unsigned short sbuf[2 * 128 * 72];
    unsigned short* At = sbuf;
    unsigned short* Bt = sbuf + 128 * 72;
    unsigned short* Ct = sbuf;  // alias, used after final sync

    const int m0 = blockIdx.x * 128, n0 = blockIdx.y * 128;
    const int tid = threadIdx.x;
    const int wv = tid >> 6, lane = tid & 63, l15 = lane & 15, q = lane >> 4;
    const int wm = wv & 1, wn = wv >> 1;

    floatx4 acc[4][4];
    for (int i = 0; i < 4; i++)
        for (int j = 0; j < 4; j++) acc[i][j] = (floatx4){0.f, 0.f, 0.f, 0.f};

    for (int k0 = 0; k0 < 512; k0 += 64) {
        for (int p = 0; p < 4; p++) {
            int idx = tid + p * 256;
            int row = idx >> 3, ch = idx & 7;
            *(short8*)&At[row * 72 + ch * 8] =
                *(const short8*)&A[(long long)(m0 + row) * lda + k0 + ch * 8];
            *(short8*)&Bt[row * 72 + ch * 8] =
                *(const short8*)&Bm[(long long)(n0 + row) * ldb + k0 + ch * 8];
        }
        __syncthreads();
        for (int ks = 0; ks < 64; ks += 32) {
            short8 af[4], bfv[4];
            for (int mi = 0; mi < 4; mi++)
                af[mi] = *(const short8*)&At[(wm * 64 + mi * 16 + l15) * 72 + ks + q * 8];
            for (int ni = 0; ni < 4; ni++)
                bfv[ni] = *(const short8*)&Bt[(wn * 64 + ni * 16 + l15) * 72 + ks + q * 8];
            for (int mi = 0; mi < 4; mi++)
                for (int ni = 0; ni < 4; ni++)
                    acc[mi][ni] = MFMA16(af[mi], bfv[ni], acc[mi][ni]);
        }
        __syncthreads();
    }

    float bv[4];
    for (int ni = 0; ni < 4; ni++)
        bv[ni] = bias ? bias[n0 + wn * 64 + ni * 16 + l15] : 0.0f;

    for (int mi = 0; mi < 4; mi++)
        for (int ni = 0; ni < 4; ni++)
            for (int r = 0; r < 4; r++)
                Ct[(wm * 64 + mi * 16 + q * 4 + r) * 128 + wn * 64 + ni * 16 + l15] =
                    f2b(acc[mi][ni][r] + bv[ni]);
    __syncthreads();

    const int tt0 = m0 & 511, bglob = m0 >> 9;
    for (int p = 0; p < 8; p++) {
        int idx = tid + p * 256;
        int row = idx >> 4, ch = idx & 15;
        if (mode) {
            int n = n0 + ch * 8;
            int gate = n >> 9, jg = (n >> 4) & 31, c0 = gate * 16 + (n & 15);
            long long dst = (((long long)(tt0 + row) * 32 + jg) * 128 + bglob) * 64 + c0;
            *(short8*)&C[dst] = *(const short8*)&Ct[row * 128 + ch * 8];
        } else {
            *(short8*)&C[(long long)(m0 + row) * ldc + n0 + ch * 8] =
                *(const short8*)&Ct[row * 128 + ch * 8];
        }
    }
}

// ---------------------------------------------------------------------------
// lstm_rec: persistent recurrence. 256 WGs = 8 batch-groups x 32 hid-groups.
// Each WG: 16 batches x 16 hidden, all 4 gates (N=64 cols). W_hh slice in
// VGPRs; c state in registers.
// Handoff per step (all relaxed agent atomics, IC-homed):
//   producer wave: raw bf16-pair ring stores -> s_waitcnt vmcnt(0) (per-wave)
//                  -> ONE sentinel word sent[slot][bg][jg*4+wv] = t
//   consumer wave: polls the 128 sentinels of its bg (one 8B load per lane,
//                  __all ballot, no sleep, no barrier) -> bulk 8x8B raw tile
//                  load -> LDS stage -> one __syncthreads -> MFMA.
// Freshness: data drained to coherence point BEFORE sentinel store; sentinel
// observed => subsequent IC-served loads see the data. Depth-2 slot reuse is
// race-free (a WG reaches t+2 only after all bg peers consumed t).
// ---------------------------------------------------------------------------
#define NBG 8
#define NJG 32
__global__ __launch_bounds__(256) void lstm_rec(
    const unsigned short* __restrict__ xg,   // [t][jg][b][c]  c = gate*16+hl
    const unsigned short* __restrict__ Whh,  // (2048, 512) bf16
    unsigned short* __restrict__ h_all,      // [b][t][h]  (128, 512, 512)
    unsigned int* __restrict__ ring,         // [2][128][256] raw bf16 pairs
    int* __restrict__ sent)                  // [2][NBG][128]  (jg*4+wv)
{
    __shared__ __align__(16) unsigned int At[2][16 * 264];  // pairs, stride 264

    const int tid = threadIdx.x;
    const int wv = tid >> 6, lane = tid & 63, l15 = lane & 15, q = lane >> 4;
    const int bg = blockIdx.x >> 5, jg = blockIdx.x & 31;
    const int b0 = bg * 16, hid0 = jg * 16;
    const int gate = l15 >> 2;                 // 0=i 1=f 2=g 3=o
    const int hl = wv * 4 + (l15 & 3);         // 0..15 within this jg
    const int hid = hid0 + hl;
    const long long jrow = (long long)gate * 512 + hid;

    short8 Wreg[16];
    for (int kk = 0; kk < 16; kk++)
        Wreg[kk] = *(const short8*)&Whh[jrow * 512 + kk * 32 + q * 8];

    float cst[4] = {0.f, 0.f, 0.f, 0.f};

    for (int t = 0; t < 512; t++) {
        // ---- prefetch xg (contiguous 2KB block per WG per step);
        //      issued before the poll so its HBM latency hides under the wait
        const long long xbase =
            (((long long)t * 32 + jg) * 128 + b0) * 64 + gate * 16 + hl;
        float xv[4];
        #pragma unroll
        for (int r = 0; r < 4; r++)
            xv[r] = b2f(xg[xbase + (long long)(q * 4 + r) * 64]);

        floatx4 acc = (floatx4){0.f, 0.f, 0.f, 0.f};
        if (t > 0) {
            const unsigned want = (unsigned)(t - 1);
            const int sl = (t - 1) & 1;
            // ---- per-wave sentinel poll: 2 sentinels per lane, one 8B load
            const unsigned long long* sp = (const unsigned long long*)
                &sent[sl * (NBG * 128) + bg * 128 + lane * 2];
            while (true) {
                unsigned long long sv = __hip_atomic_load(sp, __ATOMIC_RELAXED,
                                                          __HIP_MEMORY_SCOPE_AGENT);
                bool ok = ((unsigned)(sv & 0xFFFFFFFFull) == want) &&
                          ((unsigned)(sv >> 32) == want);
                if (__all(ok)) break;
            }
            // ---- ONE bulk flight of the raw 16KB tile: 8 x 8B per thread
            const unsigned long long* rb = (const unsigned long long*)
                (ring + sl * 32768 + b0 * 256);
            unsigned long long d[8];
            #pragma unroll
            for (int i = 0; i < 8; i++)
                d[i] = __hip_atomic_load(&rb[i * 256 + tid], __ATOMIC_RELAXED,
                                         __HIP_MEMORY_SCOPE_AGENT);
            // ---- LDS stage (straight copy, no repack)
            #pragma unroll
            for (int i = 0; i < 8; i++) {
                int widx = i * 512 + tid * 2;       // pair-word index 0..4095
                int row = widx >> 8, k = widx & 255;
                *(unsigned long long*)&At[sl][row * 264 + k] = d[i];
            }
            __syncthreads();
            const unsigned int* ap = &At[sl][l15 * 264 + q * 4];
            floatx4 a0 = (floatx4){0.f, 0.f, 0.f, 0.f};
            floatx4 a1 = (floatx4){0.f, 0.f, 0.f, 0.f};
            floatx4 a2 = (floatx4){0.f, 0.f, 0.f, 0.f};
            floatx4 a3 = (floatx4){0.f, 0.f, 0.f, 0.f};
            #pragma unroll
            for (int kk = 0; kk < 16; kk += 4) {
                a0 = MFMA16(*(const short8*)(ap + (kk + 0) * 16), Wreg[kk + 0], a0);
                a1 = MFMA16(*(const short8*)(ap + (kk + 1) * 16), Wreg[kk + 1], a1);
                a2 = MFMA16(*(const short8*)(ap + (kk + 2) * 16), Wreg[kk + 2], a2);
                a3 = MFMA16(*(const short8*)(ap + (kk + 3) * 16), Wreg[kk + 3], a3);
            }
            for (int r = 0; r < 4; r++) acc[r] = (a0[r] + a1[r]) + (a2[r] + a3[r]);
        }
        // pre-activations
        float p[4];
        #pragma unroll
        for (int r = 0; r < 4; r++) p[r] = acc[r] + xv[r];
        // gather the other gates via lane shuffles (i,f,g,o at n, n^4, n^8, n^12)
        float vf[4], vg[4], vo[4];
        #pragma unroll
        for (int r = 0; r < 4; r++) vf[r] = __shfl_xor(p[r], 4);
        #pragma unroll
        for (int r = 0; r < 4; r++) vg[r] = __shfl_xor(p[r], 8);
        #pragma unroll
        for (int r = 0; r < 4; r++) vo[r] = __shfl_xor(p[r], 12);
        if (gate == 0) {
            #pragma unroll
            for (int r = 0; r < 4; r++) {
                float ig = sigm(p[r]);
                float fg = sigm(vf[r]);
                float gv = tanh_(vg[r]);
                float og = sigm(vo[r]);
                cst[r] = fg * cst[r] + ig * gv;
                float hv = og * tanh_(cst[r]);
                unsigned short hb = f2b(hv);
                const int b = b0 + q * 4 + r;
                h_all[(long long)b * 262144 + (long long)t * 512 + hid] = hb;
                // pack even/odd hid pair into one raw 4B word, even lane stores
                unsigned partner = (unsigned)__shfl_xor((int)hb, 1);
                if ((l15 & 1) == 0) {
                    unsigned word = (unsigned)hb | (partner << 16);
                    __hip_atomic_store(&ring[(t & 1) * 32768 + b * 256 + (hid >> 1)],
                                       word, __ATOMIC_RELAXED,
                                       __HIP_MEMORY_SCOPE_AGENT);
                }
            }
        }
        // per-wave publish: drain this wave's stores, then one sentinel word
        asm volatile("s_waitcnt vmcnt(0)" ::: "memory");
        if (lane == 0)
            __hip_atomic_store(&sent[(t & 1) * (NBG * 128) + bg * 128 + jg * 4 + wv],
                               t, __ATOMIC_RELAXED, __HIP_MEMORY_SCOPE_AGENT);
    }
}

// ---------------------------------------------------------------------------
// attn_e: e[b,t] = Ve . tanh(h@U1a^T + u1b[b] + x@U2^T), fused, 32 t per WG.
// ---------------------------------------------------------------------------
__global__ __launch_bounds__(256) void attn_e(
    const unsigned short* __restrict__ h_all,
    const unsigned short* __restrict__ x_bf,
    const unsigned short* __restrict__ U1a, const unsigned short* __restrict__ U2b,
    const unsigned short* __restrict__ u1b,  // bf16 (128,512)
    const float* __restrict__ Ve,
    float* __restrict__ e)
{
    __shared__ __align__(16) unsigned short Bt[512 * 40];
    __shared__ __align__(16) unsigned short At[32 * 40];
    __shared__ float ered[4][32];

    const int tid = threadIdx.x;
    const int wv = tid >> 6, lane = tid & 63, l15 = lane & 15, q = lane >> 4;
    const int b = blockIdx.x >> 4, t0 = (blockIdx.x & 15) * 32;

    floatx4 acc[2][8];
    for (int mi = 0; mi < 2; mi++)
        for (int ni = 0; ni < 8; ni++) acc[mi][ni] = (floatx4){0.f, 0.f, 0.f, 0.f};

    for (int it = 0; it < 32; it++) {
        const int phase = it >> 4, kk = (it & 15) * 32;
        const unsigned short* Asrc = phase ? x_bf : h_all;
        const unsigned short* Bsrc = phase ? U2b : U1a;
        __syncthreads();
        for (int idx = tid; idx < 2048; idx += 256) {
            int row = idx >> 2, ch = idx & 3;
            *(short8*)&Bt[row * 40 + ch * 8] =
                *(const short8*)&Bsrc[(long long)row * 512 + kk + ch * 8];
        }
        if (tid < 128) {
            int row = tid >> 2, ch = tid & 3;
            *(short8*)&At[row * 40 + ch * 8] =
                *(const short8*)&Asrc[(long long)(b * 512 + t0 + row) * 512 + kk + ch * 8];
        }
        __syncthreads();
        short8 af[2];
        for (int mi = 0; mi < 2; mi++)
            af[mi] = *(const short8*)&At[(mi * 16 + l15) * 40 + q * 8];
        for (int ni = 0; ni < 8; ni++) {
            short8 bfv = *(const short8*)&Bt[(wv * 128 + ni * 16 + l15) * 40 + q * 8];
            acc[0][ni] = MFMA16(af[0], bfv, acc[0][ni]);
            acc[1][ni] = MFMA16(af[1], bfv, acc[1][ni]);
        }
    }

    float s[2][4] = {{0.f, 0.f, 0.f, 0.f}, {0.f, 0.f, 0.f, 0.f}};
    for (int ni = 0; ni < 8; ni++) {
        int n = wv * 128 + ni * 16 + l15;
        float ub = b2f(u1b[b * 512 + n]);
        float vev = Ve[n];
        for (int mi = 0; mi < 2; mi++)
            for (int r = 0; r < 4; r++)
                s[mi][r] += vev * tanh_(acc[mi][ni][r] + ub);
    }
    for (int off = 1; off <= 8; off <<= 1)
        for (int mi = 0; mi < 2; mi++)
            for (int r = 0; r < 4; r++) s[mi][r] += __shfl_xor(s[mi][r], off);
    if (l15 == 0)
        for (int mi = 0; mi < 2; mi++)
            for (int r = 0; r < 4; r++) ered[wv][mi * 16 + q * 4 + r] = s[mi][r];
    __syncthreads();
    if (tid < 32)
        e[(long long)b * 512 + t0 + tid] =
            ered[0][tid] + ered[1][tid] + ered[2][tid] + ered[3][tid];
}

// ---------------------------------------------------------------------------
// attn_out: softmax over T, context = alpha.h, head -> mu, sigma. 1 WG per b.
// ---------------------------------------------------------------------------
__global__ __launch_bounds__(256) void attn_out(
    const float* __restrict__ e, const unsigned short* __restrict__ h_all,
    const float* __restrict__ Wout, const float* __restrict__ bout,
    float* __restrict__ outp)
{
    __shared__ float sm[512];
    __shared__ float red[8];
    const int b = blockIdx.x, tid = threadIdx.x;
    const int wv = tid >> 6, lane = tid & 63;

    float e0 = e[b * 512 + tid], e1 = e[b * 512 + 256 + tid];
    float mx = fmaxf(e0, e1);
    for (int off = 32; off; off >>= 1) mx = fmaxf(mx, __shfl_xor(mx, off));
    if (lane == 0) red[wv] = mx;
    __syncthreads();
    mx = fmaxf(fmaxf(red[0], red[1]), fmaxf(red[2], red[3]));

    float s0 = __expf(e0 - mx), s1 = __expf(e1 - mx);
    sm[tid] = s0; sm[256 + tid] = s1;
    float ss = s0 + s1;
    for (int off = 32; off; off >>= 1) ss += __shfl_xor(ss, off);
    if (lane == 0) red[4 + wv] = ss;
    __syncthreads();
    float inv = 1.0f / (red[4] + red[5] + red[6] + red[7]);

    const long long base = (long long)b * 262144;
    float a0 = 0.f, a1 = 0.f;
    for (int t = 0; t < 512; t++) {
        float al = sm[t];
        a0 += al * b2f(h_all[base + t * 512 + tid]);
        a1 += al * b2f(h_all[base + t * 512 + 256 + tid]);
    }
    a0 *= inv; a1 *= inv;

    float q0 = a0 * Wout[tid] + a1 * Wout[256 + tid];
    float q1 = a0 * Wout[512 + tid] + a1 * Wout[768 + tid];
    for (int off = 32; off; off >>= 1) { q0 += __shfl_xor(q0, off); q1 += __shfl_xor(q1, off); }
    __syncthreads();  // red reuse
    if (lane == 0) { red[wv] = q0; red[4 + wv] = q1; }
    __syncthreads();
    if (tid == 0) {
        float P0 = red[0] + red[1] + red[2] + red[3] + bout[0];
        float P1 = red[4] + red[5] + red[6] + red[7] + bout[1];
        outp[b] = P0;
        float sp = (P1 > 15.0f) ? P1 : log1pf(__expf(P1));
        outp[128 + b] = sp + 1e-5f;
    }
}

// ---------------------------------------------------------------------------
extern "C" void kernel_launch(void* const* d_in, const int* in_sizes, int n_in,
                              void* d_out, int out_size, void* d_ws, size_t ws_size,
                              hipStream_t stream)
{
    const float* x    = (const float*)d_in[0];
    const float* Wih  = (const float*)d_in[1];
    const float* Whh  = (const float*)d_in[2];
    const float* bih  = (const float*)d_in[3];
    const float* bhh  = (const float*)d_in[4];
    const float* Ve   = (const float*)d_in[5];
    const float* U1   = (const float*)d_in[6];
    const float* U2   = (const float*)d_in[7];
    const float* Wout = (const float*)d_in[8];
    const float* bout = (const float*)d_in[9];
    float* out = (float*)d_out;

    char* ws = (char*)d_ws;
    size_t off = 0;
    auto alloc = [&](size_t bytes) -> void* {
        void* p = ws + off;
        off += (bytes + 255) & ~(size_t)255;
        return p;
    };
    unsigned short* x_bf   = (unsigned short*)alloc(33554432ull * 2);
    unsigned short* Wih_bf = (unsigned short*)alloc(1048576ull * 2);
    unsigned short* Whh_bf = (unsigned short*)alloc(1048576ull * 2);
    unsigned short* U1a    = (unsigned short*)alloc(262144ull * 2);
    unsigned short* U1b    = (unsigned short*)alloc(262144ull * 2);
    unsigned short* U2b    = (unsigned short*)alloc(262144ull * 2);
    float*          bias   = (float*)alloc(2048ull * 4);
    unsigned short* xg     = (unsigned short*)alloc(134217728ull * 2);
    unsigned short* h_all  = (unsigned short*)alloc(33554432ull * 2);
    unsigned short* u1bv   = (unsigned short*)alloc(65536ull * 2);
    float*          e      = (float*)alloc(65536ull * 4);
    unsigned int*   ring   = (unsigned int*)alloc(65536ull * 4);   // 2x128x256 raw pairs
    int*            sentf  = (int*)alloc(2048ull * 4);             // 2x8x128 sentinels
    if (off > ws_size) return;  // workspace too small: fail safe (no corruption)

    prep<<<4096, 256, 0, stream>>>(x, Wih, Whh, bih, bhh, U1, U2,
                                   x_bf, Wih_bf, Whh_bf, U1a, U1b, U2b, bias);
    // xg = x @ W_ih^T + b, scattered into [t][jg][b][c]
    gemm_bt<<<dim3(512, 16), 256, 0, stream>>>(x_bf, 512, Wih_bf, 512,
                                               xg, 2048, bias, 1);
    lstm_rec<<<256, 256, 0, stream>>>(xg, Whh_bf, h_all, ring, sentf);
    // u1b = h_last @ U1b^T
    gemm_bt<<<dim3(1, 4), 256, 0, stream>>>(h_all + 511 * 512, 262144, U1b, 512,
                                            u1bv, 512, nullptr, 0);
    attn_e<<<2048, 256, 0, stream>>>(h_all, x_bf, U1a, U2b, u1bv, Ve, e);
    attn_out<<<128, 256, 0, stream>>>(e, h_all, Wout, bout, out);
}

// Round 6
// 3644.831 us; speedup vs baseline: 1.9430x; 1.0415x over previous
//
#include <hip/hip_runtime.h>
#include <stdint.h>

// ---------------------------------------------------------------------------
// MarketScoringUnit: LSTM(B=128,T=512,H=512) + attention + (mu, sigma) head.
// Round 6 lstm_rec: 2-way batch-interleaved recurrence. 128 WGs; each WG owns
// TWO independent batch-group tiles (bg, bg+4) and alternates
// poll->MFMA->publish between them, hiding each tile's L3 exchange flight
// under the other tile's compute. Exchange = R3's eager tagged data-poll
// (detection IS the data; lowest serial latency), whose congestion collapses
// because polls now start ~1000 cyc after publish instead of immediately.
// ---------------------------------------------------------------------------

using short8  = __attribute__((ext_vector_type(8))) short;   // 8 bf16 (4 VGPRs)
using short4v = __attribute__((ext_vector_type(4))) short;
using floatx4 = __attribute__((ext_vector_type(4))) float;

#define MFMA16(a, b, c) __builtin_amdgcn_mfma_f32_16x16x32_bf16((a), (b), (c), 0, 0, 0)

__device__ __forceinline__ unsigned short f2b(float f) {
    unsigned u = __float_as_uint(f);
    u += 0x7FFFu + ((u >> 16) & 1u);           // RNE
    return (unsigned short)(u >> 16);
}
__device__ __forceinline__ float b2f(unsigned short h) {
    return __uint_as_float(((unsigned)h) << 16);
}
__device__ __forceinline__ float sigm(float x) { return 1.0f / (1.0f + __expf(-x)); }
__device__ __forceinline__ float tanh_(float x) { return 1.0f - 2.0f / (__expf(2.0f * x) + 1.0f); }

// ---------------------------------------------------------------------------
// prep: fp32 -> bf16 conversions, U1 split into U1a/U1b, bias = b_ih + b_hh
// ---------------------------------------------------------------------------
__global__ __launch_bounds__(256) void prep(
    const float* __restrict__ x, const float* __restrict__ Wih, const float* __restrict__ Whh,
    const float* __restrict__ bih, const float* __restrict__ bhh,
    const float* __restrict__ U1, const float* __restrict__ U2,
    unsigned short* __restrict__ x_bf, unsigned short* __restrict__ Wih_bf,
    unsigned short* __restrict__ Whh_bf, unsigned short* __restrict__ U1a,
    unsigned short* __restrict__ U1b, unsigned short* __restrict__ U2b,
    float* __restrict__ bias)
{
    const long long NX4 = 33554432LL / 4;  // x as float4
    const long long NREST = 1048576LL + 1048576LL + 524288LL + 262144LL + 2048LL;
    const long long total = NX4 + NREST;
    for (long long u = (long long)blockIdx.x * 256 + threadIdx.x; u < total;
         u += (long long)gridDim.x * 256) {
        if (u < NX4) {
            float4 v = ((const float4*)x)[u];
            short4v o;
            o[0] = (short)f2b(v.x); o[1] = (short)f2b(v.y);
            o[2] = (short)f2b(v.z); o[3] = (short)f2b(v.w);
            *(short4v*)&x_bf[u * 4] = o;
        } else {
            long long i = u - NX4;
            if (i < 1048576) { Wih_bf[i] = f2b(Wih[i]); continue; }
            i -= 1048576;
            if (i < 1048576) { Whh_bf[i] = f2b(Whh[i]); continue; }
            i -= 1048576;
            if (i < 524288) {
                int row = (int)(i >> 10), col = (int)(i & 1023);
                if (col < 512) U1a[row * 512 + col] = f2b(U1[i]);
                else           U1b[row * 512 + (col - 512)] = f2b(U1[i]);
                continue;
            }
            i -= 524288;
            if (i < 262144) { U2b[i] = f2b(U2[i]); continue; }
            i -= 262144;
            bias[i] = bih[i] + bhh[i];
        }
    }
}

// ---------------------------------------------------------------------------
// gemm_bt: C[m][n] = sum_k A[m][k]*B[n][k] (+bias[n]); bf16 in/out, fp32 acc.
// 128x128 block tile, BK=64, 4 waves of 64x64.
// mode==1: scatter-store into xg layout [t][jg][b][c], c = gate*16 + (n&15),
//          jg = (n>>4)&31, gate = n>>9  (tile rows = 128 consecutive t, one b)
// ---------------------------------------------------------------------------
__global__ __launch_bounds__(256) void gemm_bt(
    const unsigned short* __restrict__ A, long long lda,
    const unsigned short* __restrict__ Bm, long long ldb,
    unsigned short* __restrict__ C, long long ldc,
    const float* __restrict__ bias, int mode)
{
    __shared__ __align__(16) unsigned short sbuf[2 * 128 * 72];
    unsigned short* At = sbuf;
    unsigned short* Bt = sbuf + 128 * 72;
    unsigned short* Ct = sbuf;  // alias, used after final sync

    const int m0 = blockIdx.x * 128, n0 = blockIdx.y * 128;
    const int tid = threadIdx.x;
    const int wv = tid >> 6, lane = tid & 63, l15 = lane & 15, q = lane >> 4;
    const int wm = wv & 1, wn = wv >> 1;

    floatx4 acc[4][4];
    for (int i = 0; i < 4; i++)
        for (int j = 0; j < 4; j++) acc[i][j] = (floatx4){0.f, 0.f, 0.f, 0.f};

    for (int k0 = 0; k0 < 512; k0 += 64) {
        for (int p = 0; p < 4; p++) {
            int idx = tid + p * 256;
            int row = idx >> 3, ch = idx & 7;
            *(short8*)&At[row * 72 + ch * 8] =
                *(const short8*)&A[(long long)(m0 + row) * lda + k0 + ch * 8];
            *(short8*)&Bt[row * 72 + ch * 8] =
                *(const short8*)&Bm[(long long)(n0 + row) * ldb + k0 + ch * 8];
        }
        __syncthreads();
        for (int ks = 0; ks < 64; ks += 32) {
            short8 af[4], bfv[4];
            for (int mi = 0; mi < 4; mi++)
                af[mi] = *(const short8*)&At[(wm * 64 + mi * 16 + l15) * 72 + ks + q * 8];
            for (int ni = 0; ni < 4; ni++)
                bfv[ni] = *(const short8*)&Bt[(wn * 64 + ni * 16 + l15) * 72 + ks + q * 8];
            for (int mi = 0; mi < 4; mi++)
                for (int ni = 0; ni < 4; ni++)
                    acc[mi][ni] = MFMA16(af[mi], bfv[ni], acc[mi][ni]);
        }
        __syncthreads();
    }

    float bv[4];
    for (int ni = 0; ni < 4; ni++)
        bv[ni] = bias ? bias[n0 + wn * 64 + ni * 16 + l15] : 0.0f;

    for (int mi = 0; mi < 4; mi++)
        for (int ni = 0; ni < 4; ni++)
            for (int r = 0; r < 4; r++)
                Ct[(wm * 64 + mi * 16 + q * 4 + r) * 128 + wn * 64 + ni * 16 + l15] =
                    f2b(acc[mi][ni][r] + bv[ni]);
    __syncthreads();

    const int tt0 = m0 & 511, bglob = m0 >> 9;
    for (int p = 0; p < 8; p++) {
        int idx = tid + p * 256;
        int row = idx >> 4, ch = idx & 15;
        if (mode) {
            int n = n0 + ch * 8;
            int gate = n >> 9, jg = (n >> 4) & 31, c0 = gate * 16 + (n & 15);
            long long dst = (((long long)(tt0 + row) * 32 + jg) * 128 + bglob) * 64 + c0;
            *(short8*)&C[dst] = *(const short8*)&Ct[row * 128 + ch * 8];
        } else {
            *(short8*)&C[(long long)(m0 + row) * ldc + n0 + ch * 8] =
                *(const short8*)&Ct[row * 128 + ch * 8];
        }
    }
}

// ---------------------------------------------------------------------------
// lstm_rec: 2-way interleaved persistent recurrence.
// 128 WGs = 4 pairs x 32 hid-groups; WG handles bgA=pair and bgB=pair+4
// (16 batches x 16 hidden x 4 gates each), alternating per step.
// Exchange: 2-slot ring of tagged words (tag<<16|bf16), eager all-lane
// 64-bit relaxed-atomic polling (the poll IS the data load). No fences,
// no drains, no sentinels. Depth-2 reuse is race-free per bg chain.
// ---------------------------------------------------------------------------
__global__ __launch_bounds__(256) void lstm_rec(
    const unsigned short* __restrict__ xg,   // [t][jg][b][c]  c = gate*16+hl
    const unsigned short* __restrict__ Whh,  // (2048, 512) bf16
    unsigned short* __restrict__ h_all,      // [b][t][h]  (128, 512, 512)
    unsigned int* __restrict__ ring)         // [2][128][512] tagged words
{
    __shared__ unsigned int At[2][16 * 264];  // one buffer per half

    const int tid = threadIdx.x;
    const int wv = tid >> 6, lane = tid & 63, l15 = lane & 15, q = lane >> 4;
    const int pair = blockIdx.x >> 5, jg = blockIdx.x & 31;
    const int gate = l15 >> 2;                 // 0=i 1=f 2=g 3=o
    const int hl = wv * 4 + (l15 & 3);         // 0..15 within this jg
    const int hid = jg * 16 + hl;
    const long long jrow = (long long)gate * 512 + hid;

    short8 Wreg[16];
    for (int kk = 0; kk < 16; kk++)
        Wreg[kk] = *(const short8*)&Whh[jrow * 512 + kk * 32 + q * 8];

    float cst[2][4] = {{0.f, 0.f, 0.f, 0.f}, {0.f, 0.f, 0.f, 0.f}};

    for (int t = 0; t < 512; t++) {
        // prefetch xg for BOTH halves (independent of h; hides under polls)
        float xv[2][4];
        #pragma unroll
        for (int hf = 0; hf < 2; hf++) {
            const int b0 = (pair + hf * 4) * 16;
            const long long xbase =
                (((long long)t * 32 + jg) * 128 + b0) * 64 + gate * 16 + hl;
            #pragma unroll
            for (int r = 0; r < 4; r++)
                xv[hf][r] = b2f(xg[xbase + (long long)(q * 4 + r) * 64]);
        }

        #pragma unroll
        for (int hf = 0; hf < 2; hf++) {
            const int b0 = (pair + hf * 4) * 16;
            floatx4 acc = (floatx4){0.f, 0.f, 0.f, 0.f};
            if (t > 0) {
                const unsigned want = (unsigned)(t - 1);
                unsigned long long* rb = (unsigned long long*)
                    (ring + ((t - 1) & 1) * 65536 + b0 * 512);
                unsigned long long w[16];
                #pragma unroll
                for (int i = 0; i < 16; i++)
                    w[i] = __hip_atomic_load(&rb[tid + i * 256], __ATOMIC_RELAXED,
                                             __HIP_MEMORY_SCOPE_AGENT);
                while (true) {
                    unsigned bad = 0;
                    #pragma unroll
                    for (int i = 0; i < 16; i++) {
                        unsigned lo = (unsigned)(w[i] >> 16) & 0xFFFFu;
                        unsigned hi = (unsigned)(w[i] >> 48);
                        bad |= (lo ^ want) | (hi ^ want);
                    }
                    if (!bad) break;
                    #pragma unroll
                    for (int i = 0; i < 16; i++) {
                        unsigned lo = (unsigned)(w[i] >> 16) & 0xFFFFu;
                        unsigned hi = (unsigned)(w[i] >> 48);
                        if ((lo ^ want) | (hi ^ want))
                            w[i] = __hip_atomic_load(&rb[tid + i * 256], __ATOMIC_RELAXED,
                                                     __HIP_MEMORY_SCOPE_AGENT);
                    }
                }
                // strip tags, pack two bf16 per LDS word
                unsigned int* dst = &At[hf][0];
                #pragma unroll
                for (int i = 0; i < 16; i++) {
                    int idx = tid + i * 256;
                    int row = idx >> 8, k = idx & 255;
                    dst[row * 264 + k] =
                        (unsigned)(w[i] & 0xFFFFu) | ((unsigned)(w[i] >> 32) << 16);
                }
                __syncthreads();
                const unsigned int* ap = &At[hf][l15 * 264 + q * 4];
                floatx4 a0 = (floatx4){0.f, 0.f, 0.f, 0.f};
                floatx4 a1 = (floatx4){0.f, 0.f, 0.f, 0.f};
                floatx4 a2 = (floatx4){0.f, 0.f, 0.f, 0.f};
                floatx4 a3 = (floatx4){0.f, 0.f, 0.f, 0.f};
                #pragma unroll
                for (int kk = 0; kk < 16; kk += 4) {
                    a0 = MFMA16(*(const short8*)(ap + (kk + 0) * 16), Wreg[kk + 0], a0);
                    a1 = MFMA16(*(const short8*)(ap + (kk + 1) * 16), Wreg[kk + 1], a1);
                    a2 = MFMA16(*(const short8*)(ap + (kk + 2) * 16), Wreg[kk + 2], a2);
                    a3 = MFMA16(*(const short8*)(ap + (kk + 3) * 16), Wreg[kk + 3], a3);
                }
                for (int r = 0; r < 4; r++) acc[r] = (a0[r] + a1[r]) + (a2[r] + a3[r]);
            }
            // pre-activations
            float p[4];
            #pragma unroll
            for (int r = 0; r < 4; r++) p[r] = acc[r] + xv[hf][r];
            // gather other gates via lane shuffles (i,f,g,o at n, n^4, n^8, n^12)
            float vf[4], vg[4], vo[4];
            #pragma unroll
            for (int r = 0; r < 4; r++) vf[r] = __shfl_xor(p[r], 4);
            #pragma unroll
            for (int r = 0; r < 4; r++) vg[r] = __shfl_xor(p[r], 8);
            #pragma unroll
            for (int r = 0; r < 4; r++) vo[r] = __shfl_xor(p[r], 12);
            if (gate == 0) {
                #pragma unroll
                for (int r = 0; r < 4; r++) {
                    float ig = sigm(p[r]);
                    float fg = sigm(vf[r]);
                    float gv = tanh_(vg[r]);
                    float og = sigm(vo[r]);
                    cst[hf][r] = fg * cst[hf][r] + ig * gv;
                    float hv = og * tanh_(cst[hf][r]);
                    unsigned short hb = f2b(hv);
                    const int b = b0 + q * 4 + r;
                    __hip_atomic_store(&ring[(t & 1) * 65536 + b * 512 + hid],
                                       ((unsigned)t << 16) | hb, __ATOMIC_RELAXED,
                                       __HIP_MEMORY_SCOPE_AGENT);
                    h_all[(long long)b * 262144 + (long long)t * 512 + hid] = hb;
                }
            }
        }
    }
}

// ---------------------------------------------------------------------------
// attn_e: e[b,t] = Ve . tanh(h@U1a^T + u1b[b] + x@U2^T), fused, 32 t per WG.
// ---------------------------------------------------------------------------
__global__ __launch_bounds__(256) void attn_e(
    const unsigned short* __restrict__ h_all,
    const unsigned short* __restrict__ x_bf,
    const unsigned short* __restrict__ U1a, const unsigned short* __restrict__ U2b,
    const unsigned short* __restrict__ u1b,  // bf16 (128,512)
    const float* __restrict__ Ve,
    float* __restrict__ e)
{
    __shared__ __align__(16) unsigned short Bt[512 * 40];
    __shared__ __align__(16) unsigned short At[32 * 40];
    __shared__ float ered[4][32];

    const int tid = threadIdx.x;
    const int wv = tid >> 6, lane = tid & 63, l15 = lane & 15, q = lane >> 4;
    const int b = blockIdx.x >> 4, t0 = (blockIdx.x & 15) * 32;

    floatx4 acc[2][8];
    for (int mi = 0; mi < 2; mi++)
        for (int ni = 0; ni < 8; ni++) acc[mi][ni] = (floatx4){0.f, 0.f, 0.f, 0.f};

    for (int it = 0; it < 32; it++) {
        const int phase = it >> 4, kk = (it & 15) * 32;
        const unsigned short* Asrc = phase ? x_bf : h_all;
        const unsigned short* Bsrc = phase ? U2b : U1a;
        __syncthreads();
        for (int idx = tid; idx < 2048; idx += 256) {
            int row = idx >> 2, ch = idx & 3;
            *(short8*)&Bt[row * 40 + ch * 8] =
                *(const short8*)&Bsrc[(long long)row * 512 + kk + ch * 8];
        }
        if (tid < 128) {
            int row = tid >> 2, ch = tid & 3;
            *(short8*)&At[row * 40 + ch * 8] =
                *(const short8*)&Asrc[(long long)(b * 512 + t0 + row) * 512 + kk + ch * 8];
        }
        __syncthreads();
        short8 af[2];
        for (int mi = 0; mi < 2; mi++)
            af[mi] = *(const short8*)&At[(mi * 16 + l15) * 40 + q * 8];
        for (int ni = 0; ni < 8; ni++) {
            short8 bfv = *(const short8*)&Bt[(wv * 128 + ni * 16 + l15) * 40 + q * 8];
            acc[0][ni] = MFMA16(af[0], bfv, acc[0][ni]);
            acc[1][ni] = MFMA16(af[1], bfv, acc[1][ni]);
        }
    }

    float s[2][4] = {{0.f, 0.f, 0.f, 0.f}, {0.f, 0.f, 0.f, 0.f}};
    for (int ni = 0; ni < 8; ni++) {
        int n = wv * 128 + ni * 16 + l15;
        float ub = b2f(u1b[b * 512 + n]);
        float vev = Ve[n];
        for (int mi = 0; mi < 2; mi++)
            for (int r = 0; r < 4; r++)
                s[mi][r] += vev * tanh_(acc[mi][ni][r] + ub);
    }
    for (int off = 1; off <= 8; off <<= 1)
        for (int mi = 0; mi < 2; mi++)
            for (int r = 0; r < 4; r++) s[mi][r] += __shfl_xor(s[mi][r], off);
    if (l15 == 0)
        for (int mi = 0; mi < 2; mi++)
            for (int r = 0; r < 4; r++) ered[wv][mi * 16 + q * 4 + r] = s[mi][r];
    __syncthreads();
    if (tid < 32)
        e[(long long)b * 512 + t0 + tid] =
            ered[0][tid] + ered[1][tid] + ered[2][tid] + ered[3][tid];
}

// ---------------------------------------------------------------------------
// attn_out: softmax over T, context = alpha.h, head -> mu, sigma. 1 WG per b.
// ---------------------------------------------------------------------------
__global__ __launch_bounds__(256) void attn_out(
    const float* __restrict__ e, const unsigned short* __restrict__ h_all,
    const float* __restrict__ Wout, const float* __restrict__ bout,
    float* __restrict__ outp)
{
    __shared__ float sm[512];
    __shared__ float red[8];
    const int b = blockIdx.x, tid = threadIdx.x;
    const int wv = tid >> 6, lane = tid & 63;

    float e0 = e[b * 512 + tid], e1 = e[b * 512 + 256 + tid];
    float mx = fmaxf(e0, e1);
    for (int off = 32; off; off >>= 1) mx = fmaxf(mx, __shfl_xor(mx, off));
    if (lane == 0) red[wv] = mx;
    __syncthreads();
    mx = fmaxf(fmaxf(red[0], red[1]), fmaxf(red[2], red[3]));

    float s0 = __expf(e0 - mx), s1 = __expf(e1 - mx);
    sm[tid] = s0; sm[256 + tid] = s1;
    float ss = s0 + s1;
    for (int off = 32; off; off >>= 1) ss += __shfl_xor(ss, off);
    if (lane == 0) red[4 + wv] = ss;
    __syncthreads();
    float inv = 1.0f / (red[4] + red[5] + red[6] + red[7]);

    const long long base = (long long)b * 262144;
    float a0 = 0.f, a1 = 0.f;
    for (int t = 0; t < 512; t++) {
        float al = sm[t];
        a0 += al * b2f(h_all[base + t * 512 + tid]);
        a1 += al * b2f(h_all[base + t * 512 + 256 + tid]);
    }
    a0 *= inv; a1 *= inv;

    float q0 = a0 * Wout[tid] + a1 * Wout[256 + tid];
    float q1 = a0 * Wout[512 + tid] + a1 * Wout[768 + tid];
    for (int off = 32; off; off >>= 1) { q0 += __shfl_xor(q0, off); q1 += __shfl_xor(q1, off); }
    __syncthreads();  // red reuse
    if (lane == 0) { red[wv] = q0; red[4 + wv] = q1; }
    __syncthreads();
    if (tid == 0) {
        float P0 = red[0] + red[1] + red[2] + red[3] + bout[0];
        float P1 = red[4] + red[5] + red[6] + red[7] + bout[1];
        outp[b] = P0;
        float sp = (P1 > 15.0f) ? P1 : log1pf(__expf(P1));
        outp[128 + b] = sp + 1e-5f;
    }
}

// ---------------------------------------------------------------------------
extern "C" void kernel_launch(void* const* d_in, const int* in_sizes, int n_in,
                              void* d_out, int out_size, void* d_ws, size_t ws_size,
                              hipStream_t stream)
{
    const float* x    = (const float*)d_in[0];
    const float* Wih  = (const float*)d_in[1];
    const float* Whh  = (const float*)d_in[2];
    const float* bih  = (const float*)d_in[3];
    const float* bhh  = (const float*)d_in[4];
    const float* Ve   = (const float*)d_in[5];
    const float* U1   = (const float*)d_in[6];
    const float* U2   = (const float*)d_in[7];
    const float* Wout = (const float*)d_in[8];
    const float* bout = (const float*)d_in[9];
    float* out = (float*)d_out;

    char* ws = (char*)d_ws;
    size_t off = 0;
    auto alloc = [&](size_t bytes) -> void* {
        void* p = ws + off;
        off += (bytes + 255) & ~(size_t)255;
        return p;
    };
    unsigned short* x_bf   = (unsigned short*)alloc(33554432ull * 2);
    unsigned short* Wih_bf = (unsigned short*)alloc(1048576ull * 2);
    unsigned short* Whh_bf = (unsigned short*)alloc(1048576ull * 2);
    unsigned short* U1a    = (unsigned short*)alloc(262144ull * 2);
    unsigned short* U1b    = (unsigned short*)alloc(262144ull * 2);
    unsigned short* U2b    = (unsigned short*)alloc(262144ull * 2);
    float*          bias   = (float*)alloc(2048ull * 4);
    unsigned short* xg     = (unsigned short*)alloc(134217728ull * 2);
    unsigned short* h_all  = (unsigned short*)alloc(33554432ull * 2);
    unsigned short* u1bv   = (unsigned short*)alloc(65536ull * 2);
    float*          e      = (float*)alloc(65536ull * 4);
    unsigned int*   ring   = (unsigned int*)alloc(131072ull * 4);  // 2x128x512 tagged
    if (off > ws_size) return;  // workspace too small: fail safe (no corruption)

    prep<<<4096, 256, 0, stream>>>(x, Wih, Whh, bih, bhh, U1, U2,
                                   x_bf, Wih_bf, Whh_bf, U1a, U1b, U2b, bias);
    // xg = x @ W_ih^T + b, scattered into [t][jg][b][c]
    gemm_bt<<<dim3(512, 16), 256, 0, stream>>>(x_bf, 512, Wih_bf, 512,
                                               xg, 2048, bias, 1);
    lstm_rec<<<128, 256, 0, stream>>>(xg, Whh_bf, h_all, ring);
    // u1b = h_last @ U1b^T
    gemm_bt<<<dim3(1, 4), 256, 0, stream>>>(h_all + 511 * 512, 262144, U1b, 512,
                                            u1bv, 512, nullptr, 0);
    attn_e<<<2048, 256, 0, stream>>>(h_all, x_bf, U1a, U2b, u1bv, Ve, e);
    attn_out<<<128, 256, 0, stream>>>(e, h_all, Wout, bout, out);
}

// Round 7
// 2808.544 us; speedup vs baseline: 2.5215x; 1.2978x over previous
//
#include <hip/hip_runtime.h>
#include <stdint.h>

// ---------------------------------------------------------------------------
// MarketScoringUnit: LSTM(B=128,T=512,H=512) + attention + (mu, sigma) head.
// Round 7 lstm_rec: 64 WGs = 8 bg x 8 hid-groups; each WAVE owns 4 gates x
// 16 hidden (W_hh slice in 256 VGPRs), so i/f/g/o are in-lane (no shuffles)
// and each batch-group's exchange has only 8 producers/consumers. Eager
// tagged data-poll exchange (R3/R6 mechanism) with 4x less fabric traffic
// and 4x more MFMA per WG to hide the L3 flight.
// ---------------------------------------------------------------------------

using short8  = __attribute__((ext_vector_type(8))) short;   // 8 bf16 (4 VGPRs)
using short4v = __attribute__((ext_vector_type(4))) short;
using floatx4 = __attribute__((ext_vector_type(4))) float;

#define MFMA16(a, b, c) __builtin_amdgcn_mfma_f32_16x16x32_bf16((a), (b), (c), 0, 0, 0)

__device__ __forceinline__ unsigned short f2b(float f) {
    unsigned u = __float_as_uint(f);
    u += 0x7FFFu + ((u >> 16) & 1u);           // RNE
    return (unsigned short)(u >> 16);
}
__device__ __forceinline__ float b2f(unsigned short h) {
    return __uint_as_float(((unsigned)h) << 16);
}
__device__ __forceinline__ float sigm(float x) { return 1.0f / (1.0f + __expf(-x)); }
__device__ __forceinline__ float tanh_(float x) { return 1.0f - 2.0f / (__expf(2.0f * x) + 1.0f); }

// ---------------------------------------------------------------------------
// prep: fp32 -> bf16 conversions, U1 split into U1a/U1b, bias = b_ih + b_hh
// ---------------------------------------------------------------------------
__global__ __launch_bounds__(256) void prep(
    const float* __restrict__ x, const float* __restrict__ Wih, const float* __restrict__ Whh,
    const float* __restrict__ bih, const float* __restrict__ bhh,
    const float* __restrict__ U1, const float* __restrict__ U2,
    unsigned short* __restrict__ x_bf, unsigned short* __restrict__ Wih_bf,
    unsigned short* __restrict__ Whh_bf, unsigned short* __restrict__ U1a,
    unsigned short* __restrict__ U1b, unsigned short* __restrict__ U2b,
    float* __restrict__ bias)
{
    const long long NX4 = 33554432LL / 4;  // x as float4
    const long long NREST = 1048576LL + 1048576LL + 524288LL + 262144LL + 2048LL;
    const long long total = NX4 + NREST;
    for (long long u = (long long)blockIdx.x * 256 + threadIdx.x; u < total;
         u += (long long)gridDim.x * 256) {
        if (u < NX4) {
            float4 v = ((const float4*)x)[u];
            short4v o;
            o[0] = (short)f2b(v.x); o[1] = (short)f2b(v.y);
            o[2] = (short)f2b(v.z); o[3] = (short)f2b(v.w);
            *(short4v*)&x_bf[u * 4] = o;
        } else {
            long long i = u - NX4;
            if (i < 1048576) { Wih_bf[i] = f2b(Wih[i]); continue; }
            i -= 1048576;
            if (i < 1048576) { Whh_bf[i] = f2b(Whh[i]); continue; }
            i -= 1048576;
            if (i < 524288) {
                int row = (int)(i >> 10), col = (int)(i & 1023);
                if (col < 512) U1a[row * 512 + col] = f2b(U1[i]);
                else           U1b[row * 512 + (col - 512)] = f2b(U1[i]);
                continue;
            }
            i -= 524288;
            if (i < 262144) { U2b[i] = f2b(U2[i]); continue; }
            i -= 262144;
            bias[i] = bih[i] + bhh[i];
        }
    }
}

// ---------------------------------------------------------------------------
// gemm_bt: C[m][n] = sum_k A[m][k]*B[n][k] (+bias[n]); bf16 in/out, fp32 acc.
// 128x128 block tile, BK=64, 4 waves of 64x64.
// mode==1: scatter-store into xg layout [t][jg][b][c], c = gate*16 + (n&15),
//          jg = (n>>4)&31, gate = n>>9  (tile rows = 128 consecutive t, one b)
// ---------------------------------------------------------------------------
__global__ __launch_bounds__(256) void gemm_bt(
    const unsigned short* __restrict__ A, long long lda,
    const unsigned short* __restrict__ Bm, long long ldb,
    unsigned short* __restrict__ C, long long ldc,
    const float* __restrict__ bias, int mode)
{
    __shared__ __align__(16) unsigned short sbuf[2 * 128 * 72];
    unsigned short* At = sbuf;
    unsigned short* Bt = sbuf + 128 * 72;
    unsigned short* Ct = sbuf;  // alias, used after final sync

    const int m0 = blockIdx.x * 128, n0 = blockIdx.y * 128;
    const int tid = threadIdx.x;
    const int wv = tid >> 6, lane = tid & 63, l15 = lane & 15, q = lane >> 4;
    const int wm = wv & 1, wn = wv >> 1;

    floatx4 acc[4][4];
    for (int i = 0; i < 4; i++)
        for (int j = 0; j < 4; j++) acc[i][j] = (floatx4){0.f, 0.f, 0.f, 0.f};

    for (int k0 = 0; k0 < 512; k0 += 64) {
        for (int p = 0; p < 4; p++) {
            int idx = tid + p * 256;
            int row = idx >> 3, ch = idx & 7;
            *(short8*)&At[row * 72 + ch * 8] =
                *(const short8*)&A[(long long)(m0 + row) * lda + k0 + ch * 8];
            *(short8*)&Bt[row * 72 + ch * 8] =
                *(const short8*)&Bm[(long long)(n0 + row) * ldb + k0 + ch * 8];
        }
        __syncthreads();
        for (int ks = 0; ks < 64; ks += 32) {
            short8 af[4], bfv[4];
            for (int mi = 0; mi < 4; mi++)
                af[mi] = *(const short8*)&At[(wm * 64 + mi * 16 + l15) * 72 + ks + q * 8];
            for (int ni = 0; ni < 4; ni++)
                bfv[ni] = *(const short8*)&Bt[(wn * 64 + ni * 16 + l15) * 72 + ks + q * 8];
            for (int mi = 0; mi < 4; mi++)
                for (int ni = 0; ni < 4; ni++)
                    acc[mi][ni] = MFMA16(af[mi], bfv[ni], acc[mi][ni]);
        }
        __syncthreads();
    }

    float bv[4];
    for (int ni = 0; ni < 4; ni++)
        bv[ni] = bias ? bias[n0 + wn * 64 + ni * 16 + l15] : 0.0f;

    for (int mi = 0; mi < 4; mi++)
        for (int ni = 0; ni < 4; ni++)
            for (int r = 0; r < 4; r++)
                Ct[(wm * 64 + mi * 16 + q * 4 + r) * 128 + wn * 64 + ni * 16 + l15] =
                    f2b(acc[mi][ni][r] + bv[ni]);
    __syncthreads();

    const int tt0 = m0 & 511, bglob = m0 >> 9;
    for (int p = 0; p < 8; p++) {
        int idx = tid + p * 256;
        int row = idx >> 4, ch = idx & 15;
        if (mode) {
            int n = n0 + ch * 8;
            int gate = n >> 9, jg = (n >> 4) & 31, c0 = gate * 16 + (n & 15);
            long long dst = (((long long)(tt0 + row) * 32 + jg) * 128 + bglob) * 64 + c0;
            *(short8*)&C[dst] = *(const short8*)&Ct[row * 128 + ch * 8];
        } else {
            *(short8*)&C[(long long)(m0 + row) * ldc + n0 + ch * 8] =
                *(const short8*)&Ct[row * 128 + ch * 8];
        }
    }
}

// ---------------------------------------------------------------------------
// lstm_rec: 64 WGs = 8 bg x 8 hid-groups (jgb). Wave wv of WG (bg,jgb) owns
// hid = jgb*64 + wv*16 + l15 for ALL FOUR GATES: Wreg[ct][kk] = B-frag of
// W_hh row (ct*512 + hid), 256 VGPRs/lane, loaded once. C/D layout puts
// gate ct for (batch q*4+r, hid l15) in acc[ct][r] -> pointwise is in-lane.
// acc is initialized from xg (prefetched before the poll). Exchange: 2-slot
// tagged ring, eager all-lane 64-bit relaxed-atomic poll (detection IS the
// data), depth-2 parity reuse safe per bg chain.
// ---------------------------------------------------------------------------
__global__ __launch_bounds__(256, 1) void lstm_rec(
    const unsigned short* __restrict__ xg,   // [t][jg32][b][c]  c = gate*16+hl
    const unsigned short* __restrict__ Whh,  // (2048, 512) bf16
    unsigned short* __restrict__ h_all,      // [b][t][h]  (128, 512, 512)
    unsigned int* __restrict__ ring)         // [2][128][512] tagged words
{
    __shared__ unsigned int At[2][16 * 264];  // 16 batches x 256 pair-words

    const int tid = threadIdx.x;
    const int wv = tid >> 6, lane = tid & 63, l15 = lane & 15, q = lane >> 4;
    const int bg = blockIdx.x >> 3, jgb = blockIdx.x & 7;
    const int b0 = bg * 16;
    const int jg32 = jgb * 4 + wv;            // 16-hid group of this wave
    const int hid = jg32 * 16 + l15;          // this lane's hidden index

    // W_hh B-frags: Wreg[ct][kk], row = ct*512 + hid, k = kk*32 + q*8
    short8 Wreg[4][16];
    #pragma unroll
    for (int ct = 0; ct < 4; ct++)
        #pragma unroll
        for (int kk = 0; kk < 16; kk++)
            Wreg[ct][kk] = *(const short8*)
                &Whh[(long long)(ct * 512 + hid) * 512 + kk * 32 + q * 8];

    float cst[4] = {0.f, 0.f, 0.f, 0.f};

    for (int t = 0; t < 512; t++) {
        // ---- prefetch xg: acc-init values, 16 scalar loads (pre-poll) ----
        const long long xbase = ((long long)(t * 32 + jg32) * 128 + b0) * 64;
        floatx4 acc[4];
        #pragma unroll
        for (int ct = 0; ct < 4; ct++)
            #pragma unroll
            for (int r = 0; r < 4; r++)
                acc[ct][r] = b2f(xg[xbase + (q * 4 + r) * 64 + ct * 16 + l15]);

        if (t > 0) {
            const unsigned want = (unsigned)(t - 1);
            const int sl = (t - 1) & 1;
            unsigned long long* rb = (unsigned long long*)
                (ring + sl * 65536 + b0 * 512);
            unsigned long long w[16];
            #pragma unroll
            for (int i = 0; i < 16; i++)
                w[i] = __hip_atomic_load(&rb[tid + i * 256], __ATOMIC_RELAXED,
                                         __HIP_MEMORY_SCOPE_AGENT);
            while (true) {
                unsigned bad = 0;
                #pragma unroll
                for (int i = 0; i < 16; i++) {
                    unsigned lo = (unsigned)(w[i] >> 16) & 0xFFFFu;
                    unsigned hi = (unsigned)(w[i] >> 48);
                    bad |= (lo ^ want) | (hi ^ want);
                }
                if (!bad) break;
                #pragma unroll
                for (int i = 0; i < 16; i++) {
                    unsigned lo = (unsigned)(w[i] >> 16) & 0xFFFFu;
                    unsigned hi = (unsigned)(w[i] >> 48);
                    if ((lo ^ want) | (hi ^ want))
                        w[i] = __hip_atomic_load(&rb[tid + i * 256], __ATOMIC_RELAXED,
                                                 __HIP_MEMORY_SCOPE_AGENT);
                }
            }
            // strip tags, pack two bf16 per LDS word
            unsigned int* dst = &At[sl][0];
            #pragma unroll
            for (int i = 0; i < 16; i++) {
                int idx = tid + i * 256;
                int row = idx >> 8, k = idx & 255;
                dst[row * 264 + k] =
                    (unsigned)(w[i] & 0xFFFFu) | ((unsigned)(w[i] >> 32) << 16);
            }
            __syncthreads();
            // MFMA: A = h tile (batch l15, K), B = Wreg; 4 chains (one/gate)
            const unsigned int* ap = &At[sl][l15 * 264 + q * 4];
            #pragma unroll
            for (int kk = 0; kk < 16; kk++) {
                short8 af = *(const short8*)(ap + kk * 16);
                acc[0] = MFMA16(af, Wreg[0][kk], acc[0]);
                acc[1] = MFMA16(af, Wreg[1][kk], acc[1]);
                acc[2] = MFMA16(af, Wreg[2][kk], acc[2]);
                acc[3] = MFMA16(af, Wreg[3][kk], acc[3]);
            }
        }
        // ---- pointwise: gates are in-lane (acc[0..3] = i,f,g,o) ----
        unsigned short hbv[4];
        #pragma unroll
        for (int r = 0; r < 4; r++) {
            float ig = sigm(acc[0][r]);
            float fg = sigm(acc[1][r]);
            float gv = tanh_(acc[2][r]);
            float og = sigm(acc[3][r]);
            cst[r] = fg * cst[r] + ig * gv;
            hbv[r] = f2b(og * tanh_(cst[r]));
        }
        // publish: ring first (latency-critical), then h_all
        #pragma unroll
        for (int r = 0; r < 4; r++) {
            const int b = b0 + q * 4 + r;
            __hip_atomic_store(&ring[(t & 1) * 65536 + b * 512 + hid],
                               ((unsigned)t << 16) | hbv[r], __ATOMIC_RELAXED,
                               __HIP_MEMORY_SCOPE_AGENT);
        }
        #pragma unroll
        for (int r = 0; r < 4; r++) {
            const int b = b0 + q * 4 + r;
            h_all[(long long)b * 262144 + (long long)t * 512 + hid] = hbv[r];
        }
    }
}

// ---------------------------------------------------------------------------
// attn_e: e[b,t] = Ve . tanh(h@U1a^T + u1b[b] + x@U2^T), fused, 32 t per WG.
// ---------------------------------------------------------------------------
__global__ __launch_bounds__(256) void attn_e(
    const unsigned short* __restrict__ h_all,
    const unsigned short* __restrict__ x_bf,
    const unsigned short* __restrict__ U1a, const unsigned short* __restrict__ U2b,
    const unsigned short* __restrict__ u1b,  // bf16 (128,512)
    const float* __restrict__ Ve,
    float* __restrict__ e)
{
    __shared__ __align__(16) unsigned short Bt[512 * 40];
    __shared__ __align__(16) unsigned short At[32 * 40];
    __shared__ float ered[4][32];

    const int tid = threadIdx.x;
    const int wv = tid >> 6, lane = tid & 63, l15 = lane & 15, q = lane >> 4;
    const int b = blockIdx.x >> 4, t0 = (blockIdx.x & 15) * 32;

    floatx4 acc[2][8];
    for (int mi = 0; mi < 2; mi++)
        for (int ni = 0; ni < 8; ni++) acc[mi][ni] = (floatx4){0.f, 0.f, 0.f, 0.f};

    for (int it = 0; it < 32; it++) {
        const int phase = it >> 4, kk = (it & 15) * 32;
        const unsigned short* Asrc = phase ? x_bf : h_all;
        const unsigned short* Bsrc = phase ? U2b : U1a;
        __syncthreads();
        for (int idx = tid; idx < 2048; idx += 256) {
            int row = idx >> 2, ch = idx & 3;
            *(short8*)&Bt[row * 40 + ch * 8] =
                *(const short8*)&Bsrc[(long long)row * 512 + kk + ch * 8];
        }
        if (tid < 128) {
            int row = tid >> 2, ch = tid & 3;
            *(short8*)&At[row * 40 + ch * 8] =
                *(const short8*)&Asrc[(long long)(b * 512 + t0 + row) * 512 + kk + ch * 8];
        }
        __syncthreads();
        short8 af[2];
        for (int mi = 0; mi < 2; mi++)
            af[mi] = *(const short8*)&At[(mi * 16 + l15) * 40 + q * 8];
        for (int ni = 0; ni < 8; ni++) {
            short8 bfv = *(const short8*)&Bt[(wv * 128 + ni * 16 + l15) * 40 + q * 8];
            acc[0][ni] = MFMA16(af[0], bfv, acc[0][ni]);
            acc[1][ni] = MFMA16(af[1], bfv, acc[1][ni]);
        }
    }

    float s[2][4] = {{0.f, 0.f, 0.f, 0.f}, {0.f, 0.f, 0.f, 0.f}};
    for (int ni = 0; ni < 8; ni++) {
        int n = wv * 128 + ni * 16 + l15;
        float ub = b2f(u1b[b * 512 + n]);
        float vev = Ve[n];
        for (int mi = 0; mi < 2; mi++)
            for (int r = 0; r < 4; r++)
                s[mi][r] += vev * tanh_(acc[mi][ni][r] + ub);
    }
    for (int off = 1; off <= 8; off <<= 1)
        for (int mi = 0; mi < 2; mi++)
            for (int r = 0; r < 4; r++) s[mi][r] += __shfl_xor(s[mi][r], off);
    if (l15 == 0)
        for (int mi = 0; mi < 2; mi++)
            for (int r = 0; r < 4; r++) ered[wv][mi * 16 + q * 4 + r] = s[mi][r];
    __syncthreads();
    if (tid < 32)
        e[(long long)b * 512 + t0 + tid] =
            ered[0][tid] + ered[1][tid] + ered[2][tid] + ered[3][tid];
}

// ---------------------------------------------------------------------------
// attn_out: softmax over T, context = alpha.h, head -> mu, sigma. 1 WG per b.
// ---------------------------------------------------------------------------
__global__ __launch_bounds__(256) void attn_out(
    const float* __restrict__ e, const unsigned short* __restrict__ h_all,
    const float* __restrict__ Wout, const float* __restrict__ bout,
    float* __restrict__ outp)
{
    __shared__ float sm[512];
    __shared__ float red[8];
    const int b = blockIdx.x, tid = threadIdx.x;
    const int wv = tid >> 6, lane = tid & 63;

    float e0 = e[b * 512 + tid], e1 = e[b * 512 + 256 + tid];
    float mx = fmaxf(e0, e1);
    for (int off = 32; off; off >>= 1) mx = fmaxf(mx, __shfl_xor(mx, off));
    if (lane == 0) red[wv] = mx;
    __syncthreads();
    mx = fmaxf(fmaxf(red[0], red[1]), fmaxf(red[2], red[3]));

    float s0 = __expf(e0 - mx), s1 = __expf(e1 - mx);
    sm[tid] = s0; sm[256 + tid] = s1;
    float ss = s0 + s1;
    for (int off = 32; off; off >>= 1) ss += __shfl_xor(ss, off);
    if (lane == 0) red[4 + wv] = ss;
    __syncthreads();
    float inv = 1.0f / (red[4] + red[5] + red[6] + red[7]);

    const long long base = (long long)b * 262144;
    float a0 = 0.f, a1 = 0.f;
    for (int t = 0; t < 512; t++) {
        float al = sm[t];
        a0 += al * b2f(h_all[base + t * 512 + tid]);
        a1 += al * b2f(h_all[base + t * 512 + 256 + tid]);
    }
    a0 *= inv; a1 *= inv;

    float q0 = a0 * Wout[tid] + a1 * Wout[256 + tid];
    float q1 = a0 * Wout[512 + tid] + a1 * Wout[768 + tid];
    for (int off = 32; off; off >>= 1) { q0 += __shfl_xor(q0, off); q1 += __shfl_xor(q1, off); }
    __syncthreads();  // red reuse
    if (lane == 0) { red[wv] = q0; red[4 + wv] = q1; }
    __syncthreads();
    if (tid == 0) {
        float P0 = red[0] + red[1] + red[2] + red[3] + bout[0];
        float P1 = red[4] + red[5] + red[6] + red[7] + bout[1];
        outp[b] = P0;
        float sp = (P1 > 15.0f) ? P1 : log1pf(__expf(P1));
        outp[128 + b] = sp + 1e-5f;
    }
}

// ---------------------------------------------------------------------------
extern "C" void kernel_launch(void* const* d_in, const int* in_sizes, int n_in,
                              void* d_out, int out_size, void* d_ws, size_t ws_size,
                              hipStream_t stream)
{
    const float* x    = (const float*)d_in[0];
    const float* Wih  = (const float*)d_in[1];
    const float* Whh  = (const float*)d_in[2];
    const float* bih  = (const float*)d_in[3];
    const float* bhh  = (const float*)d_in[4];
    const float* Ve   = (const float*)d_in[5];
    const float* U1   = (const float*)d_in[6];
    const float* U2   = (const float*)d_in[7];
    const float* Wout = (const float*)d_in[8];
    const float* bout = (const float*)d_in[9];
    float* out = (float*)d_out;

    char* ws = (char*)d_ws;
    size_t off = 0;
    auto alloc = [&](size_t bytes) -> void* {
        void* p = ws + off;
        off += (bytes + 255) & ~(size_t)255;
        return p;
    };
    unsigned short* x_bf   = (unsigned short*)alloc(33554432ull * 2);
    unsigned short* Wih_bf = (unsigned short*)alloc(1048576ull * 2);
    unsigned short* Whh_bf = (unsigned short*)alloc(1048576ull * 2);
    unsigned short* U1a    = (unsigned short*)alloc(262144ull * 2);
    unsigned short* U1b    = (unsigned short*)alloc(262144ull * 2);
    unsigned short* U2b    = (unsigned short*)alloc(262144ull * 2);
    float*          bias   = (float*)alloc(2048ull * 4);
    unsigned short* xg     = (unsigned short*)alloc(134217728ull * 2);
    unsigned short* h_all  = (unsigned short*)alloc(33554432ull * 2);
    unsigned short* u1bv   = (unsigned short*)alloc(65536ull * 2);
    float*          e      = (float*)alloc(65536ull * 4);
    unsigned int*   ring   = (unsigned int*)alloc(131072ull * 4);  // 2x128x512 tagged
    if (off > ws_size) return;  // workspace too small: fail safe (no corruption)

    prep<<<4096, 256, 0, stream>>>(x, Wih, Whh, bih, bhh, U1, U2,
                                   x_bf, Wih_bf, Whh_bf, U1a, U1b, U2b, bias);
    // xg = x @ W_ih^T + b, scattered into [t][jg][b][c]
    gemm_bt<<<dim3(512, 16), 256, 0, stream>>>(x_bf, 512, Wih_bf, 512,
                                               xg, 2048, bias, 1);
    lstm_rec<<<64, 256, 0, stream>>>(xg, Whh_bf, h_all, ring);
    // u1b = h_last @ U1b^T
    gemm_bt<<<dim3(1, 4), 256, 0, stream>>>(h_all + 511 * 512, 262144, U1b, 512,
                                            u1bv, 512, nullptr, 0);
    attn_e<<<2048, 256, 0, stream>>>(h_all, x_bf, U1a, U2b, u1bv, Ve, e);
    attn_out<<<128, 256, 0, stream>>>(e, h_all, Wout, bout, out);
}